// Round 10
// baseline (495.295 us; speedup 1.0000x reference)
//
#include <hip/hip_runtime.h>

#define DEVI __device__ __forceinline__

typedef __bf16 bf16x8 __attribute__((ext_vector_type(8)));
typedef float f32x4 __attribute__((ext_vector_type(4)));
typedef unsigned short u16;
typedef unsigned long long ull;

constexpr int NN = 8192;
constexpr int EE = 262144;

// ---- workspace layout (float-unit offsets) ----
constexpr size_t OF_WT0b = 0;                        // [512][256] u16
constexpr size_t OF_WT1b = OF_WT0b + 65536;          // [128][512] u16
constexpr size_t OF_BIA0 = OF_WT1b + 32768;          // [512] f32
constexpr size_t OF_X16  = OF_BIA0 + 512;            // [8192][256] u16 (features bf16)
constexpr size_t OF_A    = OF_X16 + 1048576;         // 8MB: XWT16 -> H16 -> G16+HG16
constexpr size_t OF_D    = OF_A + 2097152;           // 2MB: HWT16[128][8192] u16
constexpr size_t OF_VEC  = OF_D + 524288;
constexpr size_t OF_SD   = OF_VEC;                   // 8192
constexpr size_t OF_R1   = OF_SD + 8192;             // [2][8192]
constexpr size_t OF_R2   = OF_R1 + 16384;            // [2][8192]
constexpr size_t OF_AG   = OF_R2 + 16384;
constexpr size_t OF_BG   = OF_AG + 8192;
constexpr size_t OF_AH   = OF_BG + 8192;
constexpr size_t OF_BH   = OF_AH + 8192;
constexpr size_t OF_SP1  = OF_BH + 8192;
constexpr size_t OF_SNR1 = OF_SP1 + 2048;
constexpr size_t OF_SP2  = OF_SNR1 + 2048;
constexpr size_t OF_SNR2 = OF_SP2 + 2048;
constexpr size_t OF_RSI  = OF_SNR2 + 2048;
constexpr size_t OF_SCAL = OF_RSI + 2048;
constexpr size_t WS_SMALL = OF_SCAL + 16;
constexpr size_t OF_E    = WS_SMALL;                 // 33.6MB: ZbS4[4 x 8192x512 u16] -> Z2p16[16 x 8192x128 u16]
constexpr size_t WS_NEED = OF_E + 8388608;           // ~176MB (ws measured ~1 GiB via poison fill)

#define SC_CE 0
#define SC_MASK 1
#define SC_ACC 2
#define SC_E1 3
#define SC_E2 4
#define SC_C1 5
#define SC_C2 6
#define SC_WD 7

DEVI u16 bf1(float f) { __bf16 h = (__bf16)f; return __builtin_bit_cast(u16, h); }
DEVI unsigned int bf2(float a, float b) {
  return (unsigned)bf1(a) | ((unsigned)bf1(b) << 16);
}
DEVI ull bf4(float4 v) {
  return (ull)bf2(v.x, v.y) | ((ull)bf2(v.z, v.w) << 32);
}
DEVI float b2f(u16 h) { return __uint_as_float(((unsigned)h) << 16); }
DEVI float lo16(unsigned w) { return __uint_as_float(w << 16); }
DEVI float hi16(unsigned w) { return __uint_as_float(w & 0xffff0000u); }
DEVI f32x4 mfma16(bf16x8 a, bf16x8 b, f32x4 c) {
  return __builtin_amdgcn_mfma_f32_16x16x32_bf16(a, b, c, 0, 0, 0);
}
DEVI float wsum64(float v) {
  #pragma unroll
  for (int m = 1; m < 64; m <<= 1) v += __shfl_xor(v, m, 64);
  return v;
}
DEVI float wmax64(float v) {
  #pragma unroll
  for (int m = 1; m < 64; m <<= 1) v = fmaxf(v, __shfl_xor(v, m, 64));
  return v;
}
DEVI int wargmax64(float v, int idx) {
  #pragma unroll
  for (int m = 1; m < 64; m <<= 1) {
    float ov = __shfl_xor(v, m, 64);
    int   oi = __shfl_xor(idx, m, 64);
    if (ov > v || (ov == v && oi < idx)) { v = ov; idx = oi; }
  }
  return idx;
}
DEVI void blockAtomicAdd(float* dst, float v) {
  __shared__ float red[4];
  const int tid = threadIdx.x;
  v = wsum64(v);
  __syncthreads();
  if ((tid & 63) == 0) red[tid >> 6] = v;
  __syncthreads();
  if (tid == 0) atomicAdd(dst, red[0] + red[1] + red[2] + red[3]);
}
DEVI float logsig(float z) {
  return fminf(z, 0.f) - log1pf(__expf(-fabsf(z)));
}

// ---------------- f32 -> bf16 bulk convert (features only) ------------------
__global__ __launch_bounds__(256)
void cvtbf(const float* __restrict__ src, u16* __restrict__ dst, long n8) {
  long stride = (long)gridDim.x * 256;
  for (long i = (long)blockIdx.x * 256 + threadIdx.x; i < n8; i += stride) {
    long off = i << 3;
    float4 a = *(const float4*)(src + off);
    float4 b = *(const float4*)(src + off + 4);
    uint4 o;
    o.x = bf2(a.x, a.y); o.y = bf2(a.z, a.w);
    o.z = bf2(b.x, b.y); o.w = bf2(b.z, b.w);
    *(uint4*)(dst + off) = o;
  }
}

// ---------------- prep: transpose/stack small weights to bf16 ----------------
__global__ void prep(const float* __restrict__ W0, const float* __restrict__ Wh0,
                     const float* __restrict__ W1, const float* __restrict__ Wh1,
                     const float* __restrict__ b0, const float* __restrict__ bh0,
                     u16* __restrict__ wt0, u16* __restrict__ wt1,
                     float* __restrict__ bias0) {
  int t = blockIdx.x * 256 + threadIdx.x;
  if (t < 131072) {
    int j = t >> 8, k = t & 255;
    wt0[t] = bf1((j < 256) ? W0[k * 256 + j] : Wh0[k * 256 + (j - 256)]);
  } else if (t < 196608) {
    int u = t - 131072;
    int j = u >> 9, k = u & 511;
    float v = 0.f;
    if (j < 64)  { if (k < 256)  v = W1 [k * 64 + j]; }
    else         { if (k >= 256) v = Wh1[(k - 256) * 64 + (j - 64)]; }
    wt1[u] = bf1(v);
  } else if (t < 197120) {
    int j = t - 196608;
    bias0[j] = (j < 256) ? b0[j] : bh0[j - 256];
  }
}

// ============ all-bf16 MFMA GEMM (both operands bf16), m97 geometry =========
// C[m,n] = sum_k A16[m,k]*B16[n,k], bf16 split-stores at Cv + z*splitStride.
template <int FM, int FN, int SWZ, int MLOC, int NLOG>
__global__ __launch_bounds__(256, 4)
void gemm_a(const u16* __restrict__ A16, const u16* __restrict__ B16,
            u16* __restrict__ Cv, int K, int Ntot, int ksteps, size_t splitStride) {
  constexpr int BM = 32 * FM, BN = 32 * FN;
  constexpr int NSEG = (BM + BN) / 16;
  constexpr int SPW = NSEG / 4;
  __shared__ __align__(16) u16 As[2][BM * 32];
  __shared__ __align__(16) u16 Bs[2][BN * 32];
  const int tid = threadIdx.x;
  const int l = tid & 63, wid = tid >> 6;
  const int wr = wid >> 1, wc = wid & 1;
  const int fr = l & 15, fg = l >> 4;

  int m0, n0;
  if (SWZ) {
    int id = blockIdx.x + gridDim.x * blockIdx.y;
    int e = id & 7, s = id >> 3;
    m0 = (e * MLOC + (s >> NLOG)) * BM;
    n0 = (s & ((1 << NLOG) - 1)) * BN;
  } else {
    m0 = blockIdx.y * BM;
    n0 = blockIdx.x * BN;
  }
  const size_t kbase = (size_t)blockIdx.z * ksteps * 32;

  const u16* gsrc[SPW];
  u16* ld0[SPW];
  u16* ld1[SPW];
  #pragma unroll
  for (int q = 0; q < SPW; ++q) {
    int s = q * 4 + wid;
    if (s < BM / 16) {
      gsrc[q] = A16 + (size_t)(m0 + s * 16 + (l & 15)) * K + kbase + ((l >> 4) << 3);
      ld0[q] = &As[0][s << 9];
      ld1[q] = &As[1][s << 9];
    } else {
      int t2 = s - BM / 16;
      gsrc[q] = B16 + (size_t)(n0 + t2 * 16 + (l & 15)) * K + kbase + ((l >> 4) << 3);
      ld0[q] = &Bs[0][t2 << 9];
      ld1[q] = &Bs[1][t2 << 9];
    }
  }
  auto stageTo = [&](int buf, int ks2) {
    int koff = ks2 * 32;
    #pragma unroll
    for (int q = 0; q < SPW; ++q) {
      u16* d = buf ? ld1[q] : ld0[q];
      __builtin_amdgcn_global_load_lds(
          (const __attribute__((address_space(1))) void*)(gsrc[q] + koff),
          (__attribute__((address_space(3))) void*)d, 16, 0, 0);
    }
  };

  f32x4 zero = {0.f, 0.f, 0.f, 0.f};
  f32x4 acc[FM][FN];
  #pragma unroll
  for (int i = 0; i < FM; ++i)
    #pragma unroll
    for (int j = 0; j < FN; ++j) acc[i][j] = zero;

  stageTo(0, 0);
  int cur = 0;
  for (int ks = 0; ks < ksteps; ++ks) {
    __syncthreads();
    if (ks + 1 < ksteps) stageTo(cur ^ 1, ks + 1);
    bf16x8 af[FM], bfv[FN];
    #pragma unroll
    for (int i = 0; i < FM; ++i)
      af[i] = *(const bf16x8*)&As[cur][((wr * FM + i) << 9) + (l << 3)];
    #pragma unroll
    for (int j = 0; j < FN; ++j)
      bfv[j] = *(const bf16x8*)&Bs[cur][((wc * FN + j) << 9) + (l << 3)];
    #pragma unroll
    for (int i = 0; i < FM; ++i)
      #pragma unroll
      for (int j = 0; j < FN; ++j)
        acc[i][j] = mfma16(af[i], bfv[j], acc[i][j]);
    cur ^= 1;
  }

  u16* outp = Cv + (size_t)blockIdx.z * splitStride;
  #pragma unroll
  for (int i = 0; i < FM; ++i)
    #pragma unroll
    for (int j = 0; j < FN; ++j)
      #pragma unroll
      for (int r = 0; r < 4; ++r) {
        int grow = m0 + wr * 16 * FM + i * 16 + (fg << 2) + r;
        int gcol = n0 + wc * 16 * FN + j * 16 + fr;
        outp[(size_t)grow * Ntot + gcol] = bf1(acc[i][j][r]);
      }
}

// ============ fused-convert GEMM: A is f32 (reg-staged cvt), B bf16 async ====
// C[m,n] = sum_k bf16(Af[m,k])*B16[n,k].  FM must be 4 (BM=128: 8 segs x 32thr).
// A-staging: thread (seg=tid>>5, sub=tid&31) owns lane-slots {sub, sub+32} of
// its seg: one row (seg*16 + (sub&15)), col blocks (sub>>4)*8 and +16.
// 4x float4 loads -> 8 bf16 casts -> 2x ds_write_b128.  B via global_load_lds.
// Same 2-buffer 1-barrier drain schedule as gemm_a.
template <int FM, int FN, int SWZ, int MLOC, int NLOG>
__global__ __launch_bounds__(256, 3)
void gemm_f(const float* __restrict__ Af, const u16* __restrict__ B16,
            u16* __restrict__ Cv, int K, int Ntot, int ksteps, size_t splitStride) {
  static_assert(FM == 4, "A reg-staging assumes BM=128");
  constexpr int BM = 32 * FM, BN = 32 * FN;
  constexpr int BSEG = BN / 16;
  constexpr int SPWB = BSEG / 4;           // B gload_lds per wave per stage
  __shared__ __align__(16) u16 As[2][BM * 32];
  __shared__ __align__(16) u16 Bs[2][BN * 32];
  const int tid = threadIdx.x;
  const int l = tid & 63, wid = tid >> 6;
  const int wr = wid >> 1, wc = wid & 1;
  const int fr = l & 15, fg = l >> 4;

  int m0, n0;
  if (SWZ) {
    int id = blockIdx.x + gridDim.x * blockIdx.y;
    int e = id & 7, s = id >> 3;
    m0 = (e * MLOC + (s >> NLOG)) * BM;
    n0 = (s & ((1 << NLOG) - 1)) * BN;
  } else {
    m0 = blockIdx.y * BM;
    n0 = blockIdx.x * BN;
  }
  const size_t kbase = (size_t)blockIdx.z * ksteps * 32;

  // A descriptors
  const int seg = tid >> 5, sub = tid & 31;
  const float* arow = Af + (size_t)(m0 + seg * 16 + (sub & 15)) * K + kbase
                        + ((sub >> 4) << 3);
  const int awo0 = (seg << 9) + (sub << 3);          // u16 idx for slot sub
  const int awo1 = (seg << 9) + ((sub + 32) << 3);   // slot sub+32 (cols +16)

  // B descriptors (gload_lds, wave-uniform LDS dest)
  const u16* gsrcB[SPWB];
  u16* lb0[SPWB];
  u16* lb1[SPWB];
  #pragma unroll
  for (int q = 0; q < SPWB; ++q) {
    int t2 = q * 4 + wid;
    gsrcB[q] = B16 + (size_t)(n0 + t2 * 16 + (l & 15)) * K + kbase + ((l >> 4) << 3);
    lb0[q] = &Bs[0][t2 << 9];
    lb1[q] = &Bs[1][t2 << 9];
  }
  auto stageB = [&](int buf, int ks2) {
    int koff = ks2 * 32;
    #pragma unroll
    for (int q = 0; q < SPWB; ++q) {
      u16* d = buf ? lb1[q] : lb0[q];
      __builtin_amdgcn_global_load_lds(
          (const __attribute__((address_space(1))) void*)(gsrcB[q] + koff),
          (__attribute__((address_space(3))) void*)d, 16, 0, 0);
    }
  };

  float4 ra0, ra1, ra2, ra3;
  auto loadA = [&](int koff) {
    const float* p = arow + koff;
    ra0 = *(const float4*)p;
    ra1 = *(const float4*)(p + 4);
    ra2 = *(const float4*)(p + 16);
    ra3 = *(const float4*)(p + 20);
  };
  auto writeA = [&](int buf) {
    uint4 a, b;
    a.x = bf2(ra0.x, ra0.y); a.y = bf2(ra0.z, ra0.w);
    a.z = bf2(ra1.x, ra1.y); a.w = bf2(ra1.z, ra1.w);
    b.x = bf2(ra2.x, ra2.y); b.y = bf2(ra2.z, ra2.w);
    b.z = bf2(ra3.x, ra3.y); b.w = bf2(ra3.z, ra3.w);
    *(uint4*)&As[buf][awo0] = a;
    *(uint4*)&As[buf][awo1] = b;
  };

  f32x4 zero = {0.f, 0.f, 0.f, 0.f};
  f32x4 acc[FM][FN];
  #pragma unroll
  for (int i = 0; i < FM; ++i)
    #pragma unroll
    for (int j = 0; j < FN; ++j) acc[i][j] = zero;

  loadA(0);
  writeA(0);
  stageB(0, 0);
  if (ksteps > 1) loadA(32);

  int cur = 0;
  for (int ks = 0; ks < ksteps; ++ks) {
    __syncthreads();                       // buf[cur] complete (ds + gload_lds)
    if (ks + 1 < ksteps) {
      writeA(cur ^ 1);                     // regs hold A(ks+1)
      stageB(cur ^ 1, ks + 1);
    }
    if (ks + 2 < ksteps) loadA((ks + 2) * 32);
    bf16x8 af[FM], bfv[FN];
    #pragma unroll
    for (int i = 0; i < FM; ++i)
      af[i] = *(const bf16x8*)&As[cur][((wr * FM + i) << 9) + (l << 3)];
    #pragma unroll
    for (int j = 0; j < FN; ++j)
      bfv[j] = *(const bf16x8*)&Bs[cur][((wc * FN + j) << 9) + (l << 3)];
    #pragma unroll
    for (int i = 0; i < FM; ++i)
      #pragma unroll
      for (int j = 0; j < FN; ++j)
        acc[i][j] = mfma16(af[i], bfv[j], acc[i][j]);
    cur ^= 1;
  }

  u16* outp = Cv + (size_t)blockIdx.z * splitStride;
  #pragma unroll
  for (int i = 0; i < FM; ++i)
    #pragma unroll
    for (int j = 0; j < FN; ++j)
      #pragma unroll
      for (int r = 0; r < 4; ++r) {
        int grow = m0 + wr * 16 * FM + i * 16 + (fg << 2) + r;
        int gcol = n0 + wc * 16 * FN + j * 16 + fr;
        outp[(size_t)grow * Ntot + gcol] = bf1(acc[i][j][r]);
      }
}

// -------- relu+bias + NS-way split-reduce: H16 = bf16(relu(sum Z_s + bias)) --
template <int NS>
__global__ __launch_bounds__(256)
void relupack(const u16* __restrict__ z, const float* __restrict__ bias,
              u16* __restrict__ h16) {
  int t = blockIdx.x * 256 + threadIdx.x;
  int off = t << 3;
  int col = off & 511;
  float4 c0 = *(const float4*)(bias + col);
  float4 c1 = *(const float4*)(bias + col + 4);
  float r[8] = {c0.x, c0.y, c0.z, c0.w, c1.x, c1.y, c1.z, c1.w};
  #pragma unroll
  for (int s = 0; s < NS; ++s) {
    uint4 a = *(const uint4*)(z + (size_t)s * 8192 * 512 + off);
    r[0] += lo16(a.x); r[1] += hi16(a.x);
    r[2] += lo16(a.y); r[3] += hi16(a.y);
    r[4] += lo16(a.z); r[5] += hi16(a.z);
    r[6] += lo16(a.w); r[7] += hi16(a.w);
  }
  uint4 o;
  o.x = bf2(fmaxf(r[0], 0.f), fmaxf(r[1], 0.f));
  o.y = bf2(fmaxf(r[2], 0.f), fmaxf(r[3], 0.f));
  o.z = bf2(fmaxf(r[4], 0.f), fmaxf(r[5], 0.f));
  o.w = bf2(fmaxf(r[6], 0.f), fmaxf(r[7], 0.f));
  *(uint4*)(h16 + off) = o;
}

// ------- per-row epilogue: reduce NS bf16 splits, norms, CE ------------------
template <int NS>
__global__ __launch_bounds__(256)
void rowstats(const u16* __restrict__ Z2p, const float* __restrict__ b1,
              const float* __restrict__ bh1, const float* __restrict__ labels,
              const int* __restrict__ mask, const float* __restrict__ Wc,
              float* __restrict__ outp, u16* __restrict__ gcn16, u16* __restrict__ hgcn16,
              float* __restrict__ sd, float* __restrict__ ag, float* __restrict__ bg,
              float* __restrict__ ah, float* __restrict__ bh, float* __restrict__ scal) {
  const int tid = threadIdx.x, l = tid & 63, w = tid >> 6;
  const float wa = Wc[l], wb = Wc[64 + l];
  const float bb1 = b1[l], bbh1 = bh1[l];
  float s_ce = 0.f, s_mk = 0.f, s_ac = 0.f;
  for (int it = 0; it < 8; ++it) {
    int row = blockIdx.x * 32 + it * 4 + w;
    float h1 = bb1, hg = bbh1;
    #pragma unroll
    for (int s = 0; s < NS; ++s) {
      h1 += b2f(Z2p[(size_t)s * 1048576 + row * 128 + l]);
      hg += b2f(Z2p[(size_t)s * 1048576 + row * 128 + 64 + l]);
    }
    float n1 = wsum64(h1 * h1);
    float gn = h1 / fmaxf(sqrtf(n1), 1e-12f);
    float n2 = wsum64(hg * hg);
    float hn = hg / fmaxf(sqrtf(n2), 1e-12f);
    float oc = 0.6f * gn + 0.4f * hn;
    float n3 = wsum64(oc * oc);
    float o = oc / fmaxf(sqrtf(n3), 1e-12f);
    size_t ro = (size_t)row * 64 + l;
    outp[ro] = o; gcn16[ro] = bf1(gn); hgcn16[ro] = bf1(hn);
    float sdv = wsum64(gn * hn);
    float vag = wsum64(gn * wa), vbg = wsum64(gn * wb);
    float vah = wsum64(hn * wa), vbh = wsum64(hn * wb);
    float lab = labels[ro];
    float mx = wmax64(o);
    float se = wsum64(__expf(o - mx));
    float lse = mx + __logf(se);
    float slab = wsum64(lab);
    float slo = wsum64(lab * o);
    int am_o = wargmax64(o, l);
    int am_l = wargmax64(lab, l);
    if (l == 0) {
      sd[row] = sdv; ag[row] = vag; bg[row] = vbg; ah[row] = vah; bh[row] = vbh;
      float mk = (float)mask[row];
      s_ce += (lse * slab - slo) * mk;
      s_mk += mk;
      s_ac += (am_o == am_l) ? mk : 0.f;
    }
  }
  blockAtomicAdd(&scal[SC_CE], s_ce);
  blockAtomicAdd(&scal[SC_MASK], s_mk);
  blockAtomicAdd(&scal[SC_ACC], s_ac);
}

// ------- rowsum of exp(A@B^T/tau), 2 dirs x 2 n-halves (partials) -----------
__global__ __launch_bounds__(256)
void rowsumexp2(const u16* __restrict__ G16, const u16* __restrict__ H16,
                float* __restrict__ R1, float* __restrict__ R2) {
  constexpr int PK = 72;
  __shared__ __align__(16) u16 At[64 * PK];
  __shared__ __align__(16) u16 Bt[64 * PK];
  const int bx = blockIdx.x;
  const int nh = bx >> 8, r = bx & 255, dir = r >> 7;
  const u16* __restrict__ A = dir ? H16 : G16;
  const u16* __restrict__ B = dir ? G16 : H16;
  float* __restrict__ out = (dir ? R2 : R1) + nh * 8192;
  const int tid = threadIdx.x, l = tid & 63, w = tid >> 6;
  const int m0 = (r & 127) * 64;
  #pragma unroll
  for (int p = 0; p < 2; ++p) {
    int idx = p * 256 + tid, row = idx >> 3, kq = (idx & 7) << 3;
    *(uint4*)&At[row * PK + kq] = *(const uint4*)(A + (size_t)(m0 + row) * 64 + kq);
  }
  __syncthreads();
  const int fr = l & 15, fg = l >> 4;
  bf16x8 a0 = *(const bf16x8*)&At[(w * 16 + fr) * PK + (fg << 3)];
  bf16x8 a1 = *(const bf16x8*)&At[(w * 16 + fr) * PK + 32 + (fg << 3)];
  float rs0 = 0.f, rs1 = 0.f, rs2 = 0.f, rs3 = 0.f;
  const int nbeg = nh * 4096;
  for (int n0 = nbeg; n0 < nbeg + 4096; n0 += 64) {
    __syncthreads();
    #pragma unroll
    for (int p = 0; p < 2; ++p) {
      int idx = p * 256 + tid, row = idx >> 3, kq = (idx & 7) << 3;
      *(uint4*)&Bt[row * PK + kq] = *(const uint4*)(B + (size_t)(n0 + row) * 64 + kq);
    }
    __syncthreads();
    #pragma unroll
    for (int jn = 0; jn < 4; ++jn) {
      bf16x8 b0 = *(const bf16x8*)&Bt[(jn * 16 + fr) * PK + (fg << 3)];
      bf16x8 b1 = *(const bf16x8*)&Bt[(jn * 16 + fr) * PK + 32 + (fg << 3)];
      f32x4 c = {0.f, 0.f, 0.f, 0.f};
      c = mfma16(a0, b0, c);
      c = mfma16(a1, b1, c);
      rs0 += __expf(c[0] * 2.0f);
      rs1 += __expf(c[1] * 2.0f);
      rs2 += __expf(c[2] * 2.0f);
      rs3 += __expf(c[3] * 2.0f);
    }
  }
  #pragma unroll
  for (int m = 1; m < 16; m <<= 1) {
    rs0 += __shfl_xor(rs0, m, 64);
    rs1 += __shfl_xor(rs1, m, 64);
    rs2 += __shfl_xor(rs2, m, 64);
    rs3 += __shfl_xor(rs3, m, 64);
  }
  if (fr == 0) {
    int rb = m0 + w * 16 + fg * 4;
    out[rb + 0] = rs0; out[rb + 1] = rs1; out[rb + 2] = rs2; out[rb + 3] = rs3;
  }
}

// ---------------- supervised contra, 2 dirs x 4 n-chunks --------------------
__global__ __launch_bounds__(256)
void supstats2(const u16* __restrict__ G16, const u16* __restrict__ H16,
               const int* __restrict__ tidx,
               const float* __restrict__ Wi_g, const float* __restrict__ We_g,
               float* __restrict__ SP1, float* __restrict__ SNR1,
               float* __restrict__ SP2, float* __restrict__ SNR2) {
  constexpr int PK = 72;
  __shared__ __align__(16) u16 At[64 * PK];
  __shared__ __align__(16) u16 Bt[64 * PK];
  __shared__ float Ws0[64 * 68];
  __shared__ float Ws1[64 * 68];
  const int bx = blockIdx.x;
  const int chunk = bx >> 6, sub = bx & 63, dir = sub >> 5;
  const u16* __restrict__ A = dir ? H16 : G16;
  const u16* __restrict__ B = dir ? G16 : H16;
  float* __restrict__ sp_out  = dir ? SP2 : SP1;
  float* __restrict__ sn_out  = dir ? SNR2 : SNR1;
  const int tid = threadIdx.x, l = tid & 63, w = tid >> 6;
  const int m0 = (sub & 31) * 64;
  #pragma unroll
  for (int p = 0; p < 2; ++p) {
    int idx = p * 256 + tid, row = idx >> 3, kq = (idx & 7) << 3;
    int gr = tidx[m0 + row];
    *(uint4*)&At[row * PK + kq] = *(const uint4*)(A + (size_t)gr * 64 + kq);
  }
  __syncthreads();
  const int fr = l & 15, fg = l >> 4;
  bf16x8 a0 = *(const bf16x8*)&At[(w * 16 + fr) * PK + (fg << 3)];
  bf16x8 a1 = *(const bf16x8*)&At[(w * 16 + fr) * PK + 32 + (fg << 3)];
  float sp0 = 0, sp1 = 0, sp2 = 0, sp3 = 0, sn0 = 0, sn1 = 0, sn2 = 0, sn3 = 0;
  const int nbeg = chunk * 512;
  for (int n0 = nbeg; n0 < nbeg + 512; n0 += 64) {
    __syncthreads();
    #pragma unroll
    for (int p = 0; p < 2; ++p) {
      int idx = p * 256 + tid, row = idx >> 3, kq = (idx & 7) << 3;
      int gr = tidx[n0 + row];
      *(uint4*)&Bt[row * PK + kq] = *(const uint4*)(B + (size_t)gr * 64 + kq);
    }
    #pragma unroll
    for (int p = 0; p < 4; ++p) {
      int idx = p * 256 + tid, row = idx >> 4, kq = (idx & 15) << 2;
      *(float4*)&Ws0[row * 68 + kq] = *(const float4*)(Wi_g + (size_t)(m0 + row) * 2048 + n0 + kq);
      *(float4*)&Ws1[row * 68 + kq] = *(const float4*)(We_g + (size_t)(m0 + row) * 2048 + n0 + kq);
    }
    __syncthreads();
    #pragma unroll
    for (int jn = 0; jn < 4; ++jn) {
      bf16x8 b0 = *(const bf16x8*)&Bt[(jn * 16 + fr) * PK + (fg << 3)];
      bf16x8 b1 = *(const bf16x8*)&Bt[(jn * 16 + fr) * PK + 32 + (fg << 3)];
      f32x4 c = {0.f, 0.f, 0.f, 0.f};
      c = mfma16(a0, b0, c);
      c = mfma16(a1, b1, c);
      int cl = jn * 16 + fr;
      int rl = w * 16 + fg * 4;
      float e0 = __expf(c[0] * 2.0f);
      float e1 = __expf(c[1] * 2.0f);
      float e2 = __expf(c[2] * 2.0f);
      float e3 = __expf(c[3] * 2.0f);
      sp0 += e0 * Ws0[(rl + 0) * 68 + cl]; sn0 += e0 * Ws1[(rl + 0) * 68 + cl];
      sp1 += e1 * Ws0[(rl + 1) * 68 + cl]; sn1 += e1 * Ws1[(rl + 1) * 68 + cl];
      sp2 += e2 * Ws0[(rl + 2) * 68 + cl]; sn2 += e2 * Ws1[(rl + 2) * 68 + cl];
      sp3 += e3 * Ws0[(rl + 3) * 68 + cl]; sn3 += e3 * Ws1[(rl + 3) * 68 + cl];
    }
  }
  #pragma unroll
  for (int m = 1; m < 16; m <<= 1) {
    sp0 += __shfl_xor(sp0, m, 64); sn0 += __shfl_xor(sn0, m, 64);
    sp1 += __shfl_xor(sp1, m, 64); sn1 += __shfl_xor(sn1, m, 64);
    sp2 += __shfl_xor(sp2, m, 64); sn2 += __shfl_xor(sn2, m, 64);
    sp3 += __shfl_xor(sp3, m, 64); sn3 += __shfl_xor(sn3, m, 64);
  }
  if (fr == 0) {
    int rb = m0 + w * 16 + fg * 4;
    atomicAdd(&sp_out[rb + 0], sp0); atomicAdd(&sn_out[rb + 0], sn0);
    atomicAdd(&sp_out[rb + 1], sp1); atomicAdd(&sn_out[rb + 1], sn1);
    atomicAdd(&sp_out[rb + 2], sp2); atomicAdd(&sn_out[rb + 2], sn2);
    atomicAdd(&sp_out[rb + 3], sp3); atomicAdd(&sn_out[rb + 3], sn3);
  }
}

// ---------------- small reductions ----------------
__global__ __launch_bounds__(256)
void rowsum2048(const float* __restrict__ Wi, float* __restrict__ rsi) {
  int l = threadIdx.x & 63, w = threadIdx.x >> 6;
  int row = blockIdx.x * 4 + w;
  float s = 0.f;
  #pragma unroll
  for (int p = 0; p < 8; ++p) {
    int c = (p * 64 + l) << 2;
    float4 v = *(const float4*)(Wi + (size_t)row * 2048 + c);
    s += v.x + v.y + v.z + v.w;
  }
  s = wsum64(s);
  if (l == 0) rsi[row] = s;
}

__global__ __launch_bounds__(256)
void edgered(const int* __restrict__ ei, const int* __restrict__ ej,
             const float* __restrict__ ag, const float* __restrict__ bg,
             const float* __restrict__ ah, const float* __restrict__ bh,
             const float* __restrict__ bc, float* __restrict__ scal) {
  int t = blockIdx.x * 256 + threadIdx.x;
  float bcv = bc[0];
  float s1 = 0.f, s2 = 0.f;
  for (int e = t; e < EE; e += 65536) {
    int i = ei[e], j = ej[e];
    s1 += logsig(ag[i] + bh[j] + bcv);
    s2 += logsig(ah[i] + bg[j] + bcv);
  }
  blockAtomicAdd(&scal[SC_E1], s1);
  blockAtomicAdd(&scal[SC_E2], s2);
}

__global__ __launch_bounds__(256)
void contrared(const float* __restrict__ sd, const float* __restrict__ r1,
               const float* __restrict__ r2, float* __restrict__ scal) {
  int i = blockIdx.x * 256 + threadIdx.x;
  constexpr float LOGN = 9.01091334728f;  // ln(8192)
  float ra = r1[i] + r1[8192 + i];
  float rb = r2[i] + r2[8192 + i];
  float v = 4.f * sd[i] - __logf(ra) - __logf(rb) + 2.f * LOGN;
  blockAtomicAdd(&scal[SC_C1], v);
}

__global__ __launch_bounds__(256)
void supred(const float* __restrict__ sp1, const float* __restrict__ snr1,
            const float* __restrict__ sp2, const float* __restrict__ snr2,
            const float* __restrict__ rsi, float* __restrict__ scal) {
  int i = blockIdx.x * 256 + threadIdx.x;
  float rs = rsi[i];
  float a1 = sp1[i], d1 = (snr1[i] + a1) * (1.f / 2047.f);
  float a2 = sp2[i], d2 = (snr2[i] + a2) * (1.f / 2047.f);
  float v = __logf(a1 / rs / d1) + __logf(a2 / rs / d2);
  blockAtomicAdd(&scal[SC_C2], v);
}

__global__ __launch_bounds__(256)
void wdsum(const float* __restrict__ W0, const float* __restrict__ b0,
           const float* __restrict__ W1, const float* __restrict__ b1,
           const float* __restrict__ Wc, const float* __restrict__ bc,
           float* __restrict__ scal) {
  int t = threadIdx.x;
  float s = 0.f;
  for (int i = t; i < 16384; i += 256) {
    float4 v = *(const float4*)(W0 + i * 4);
    s += v.x * v.x + v.y * v.y + v.z * v.z + v.w * v.w;
  }
  for (int i = t; i < 4096; i += 256) {
    float4 v = *(const float4*)(W1 + i * 4);
    s += v.x * v.x + v.y * v.y + v.z * v.z + v.w * v.w;
  }
  if (t < 256) { float v = b0[t]; s += v * v; }
  if (t < 64)  { float v = b1[t]; s += v * v; }
  if (t < 128) { float v = Wc[t]; s += v * v; }
  if (t == 0)  { float v = bc[0]; s += v * v; }
  blockAtomicAdd(&scal[SC_WD], s);
}

__global__ void finalk(const float* __restrict__ scal, float* __restrict__ dst) {
  float masks = scal[SC_MASK];
  float loss = scal[SC_CE] / masks
             + 0.4f * (-(scal[SC_E1] + scal[SC_E2]) * (1.f / 262144.f))
             - 0.9f * scal[SC_C1] * (1.f / 16384.f)
             - 0.9f * scal[SC_C2] * (1.f / 4096.f)
             + 5e-4f * 0.5f * scal[SC_WD];
  dst[0] = loss;
  dst[1] = scal[SC_ACC] / masks;
}

extern "C" void kernel_launch(void* const* d_in, const int* in_sizes, int n_in,
                              void* d_out, int out_size, void* d_ws, size_t ws_size,
                              hipStream_t stream) {
  const float* features = (const float*)d_in[0];
  const float* support  = (const float*)d_in[1];
  const float* labels   = (const float*)d_in[2];
  const float* intra    = (const float*)d_in[3];
  const float* inter    = (const float*)d_in[4];
  const float* W0  = (const float*)d_in[5];
  const float* b0  = (const float*)d_in[6];
  const float* W1  = (const float*)d_in[7];
  const float* b1  = (const float*)d_in[8];
  const float* Wh0 = (const float*)d_in[9];
  const float* bh0 = (const float*)d_in[10];
  const float* Wh1 = (const float*)d_in[11];
  const float* bh1 = (const float*)d_in[12];
  const float* Wc  = (const float*)d_in[13];
  const float* bc  = (const float*)d_in[14];
  const int* ei    = (const int*)d_in[15];
  const int* ej    = (const int*)d_in[16];
  const int* tidx  = (const int*)d_in[17];
  const int* mask  = (const int*)d_in[18];

  if (ws_size < WS_NEED * sizeof(float)) return;  // ws measured ~1 GiB; need ~176MB

  float* ws = (float*)d_ws;
  u16*   WT0b  = (u16*)(ws + OF_WT0b);
  u16*   WT1b  = (u16*)(ws + OF_WT1b);
  float* BIA0  = ws + OF_BIA0;
  u16*   X16   = (u16*)(ws + OF_X16);   // [8192][256]
  u16*   XWT16 = (u16*)(ws + OF_A);     // [512][8192]
  u16*   H16   = (u16*)(ws + OF_A);     // [8192][512] (alias; XWT16 dead)
  u16*   HWT16 = (u16*)(ws + OF_D);     // [128][8192]
  u16*   G16   = (u16*)(ws + OF_A);               // [8192][64]
  u16*   HG16  = (u16*)(ws + OF_A + 262144);      // [8192][64]
  u16*   ZbS4  = (u16*)(ws + OF_E);     // 4 x [8192][512] splits
  u16*   Z2p16 = (u16*)(ws + OF_E);     // 16 x [8192][128] splits (ZbS4 dead)
  float* SD   = ws + OF_SD;
  float* R1   = ws + OF_R1;
  float* R2   = ws + OF_R2;
  float* AG   = ws + OF_AG;
  float* BG   = ws + OF_BG;
  float* AH   = ws + OF_AH;
  float* BH   = ws + OF_BH;
  float* SP1  = ws + OF_SP1;
  float* SNR1 = ws + OF_SNR1;
  float* SP2  = ws + OF_SP2;
  float* SNR2 = ws + OF_SNR2;
  float* RSI  = ws + OF_RSI;
  float* SCAL = ws + OF_SCAL;
  float* outp = (float*)d_out;

  hipMemsetAsync(SCAL, 0, 16 * sizeof(float), stream);
  hipMemsetAsync(SP1, 0, 4 * 2048 * sizeof(float), stream);
  prep<<<770, 256, 0, stream>>>(W0, Wh0, W1, Wh1, b0, bh0, WT0b, WT1b, BIA0);
  cvtbf<<<256, 256, 0, stream>>>(features, X16, 262144);

  // gemm1: XWT16[512][8192] = bf16((X @ [W0|Wh0])^T)  128x128 tile, ksteps=8
  gemm_a<4, 4, 0, 0, 0><<<dim3(64, 4, 1), 256, 0, stream>>>(
      WT0b, X16, XWT16, 256, 8192, 8, 0);

  // gemm2: ZbS4[z] = bf16(S(f32) @ XW partial), split-K=4, fused A-convert
  gemm_f<4, 4, 1, 8, 2><<<dim3(4, 64, 4), 256, 0, stream>>>(
      support, XWT16, ZbS4, 8192, 512, 64, (size_t)8192 * 512);
  relupack<4><<<2048, 256, 0, stream>>>(ZbS4, BIA0, H16);

  // gemm3: HWT16[128][8192] = bf16(([h0@W1 | g0@Wh1])^T)  64x128, ksteps=16
  gemm_a<2, 4, 0, 0, 0><<<dim3(64, 2, 1), 256, 0, stream>>>(
      WT1b, H16, HWT16, 512, 8192, 16, 0);

  // gemm4: Z2p16[z] = bf16(S(f32) @ HW partial), split-K=16, fused A-convert
  gemm_f<4, 4, 1, 8, 0><<<dim3(1, 64, 16), 256, 0, stream>>>(
      support, HWT16, Z2p16, 8192, 128, 16, (size_t)8192 * 128);
  rowstats<16><<<256, 256, 0, stream>>>(Z2p16, b1, bh1, labels, mask, Wc,
                                        outp, G16, HG16, SD, AG, BG, AH, BH, SCAL);

  rowsumexp2<<<512, 256, 0, stream>>>(G16, HG16, R1, R2);
  rowsum2048<<<512, 256, 0, stream>>>(intra, RSI);
  supstats2<<<256, 256, 0, stream>>>(G16, HG16, tidx, intra, inter,
                                     SP1, SNR1, SP2, SNR2);
  edgered<<<256, 256, 0, stream>>>(ei, ej, AG, BG, AH, BH, bc, SCAL);
  contrared<<<32, 256, 0, stream>>>(SD, R1, R2, SCAL);
  supred<<<8, 256, 0, stream>>>(SP1, SNR1, SP2, SNR2, RSI, SCAL);
  wdsum<<<1, 256, 0, stream>>>(W0, b0, W1, b1, Wc, bc, SCAL);
  finalk<<<1, 1, 0, stream>>>(SCAL, outp + (size_t)8192 * 64);
}

// Round 11
// 427.665 us; speedup vs baseline: 1.1581x; 1.1581x over previous
//
#include <hip/hip_runtime.h>

#define DEVI __device__ __forceinline__

typedef __bf16 bf16x8 __attribute__((ext_vector_type(8)));
typedef float f32x4 __attribute__((ext_vector_type(4)));
typedef unsigned short u16;
typedef unsigned long long ull;

constexpr int NN = 8192;
constexpr int EE = 262144;

// ---- workspace layout (float-unit offsets) ----
constexpr size_t OF_WT0b = 0;                        // [512][256] u16
constexpr size_t OF_WT1b = OF_WT0b + 65536;          // [128][512] u16
constexpr size_t OF_BIA0 = OF_WT1b + 32768;          // [512] f32
constexpr size_t OF_X16  = OF_BIA0 + 512;            // [8192][256] u16 (features bf16)
constexpr size_t OF_A    = OF_X16 + 1048576;         // 8MB: XWT16 -> H16 -> G16+HG16
constexpr size_t OF_D    = OF_A + 2097152;           // 2MB: HWT16[128][8192] u16
constexpr size_t OF_VEC  = OF_D + 524288;
constexpr size_t OF_SD   = OF_VEC;                   // 8192
constexpr size_t OF_R1   = OF_SD + 8192;             // [2][8192]
constexpr size_t OF_R2   = OF_R1 + 16384;            // [2][8192]
constexpr size_t OF_AG   = OF_R2 + 16384;
constexpr size_t OF_BG   = OF_AG + 8192;
constexpr size_t OF_AH   = OF_BG + 8192;
constexpr size_t OF_BH   = OF_AH + 8192;
constexpr size_t OF_SP1  = OF_BH + 8192;
constexpr size_t OF_SNR1 = OF_SP1 + 2048;
constexpr size_t OF_SP2  = OF_SNR1 + 2048;
constexpr size_t OF_SNR2 = OF_SP2 + 2048;
constexpr size_t OF_RSI  = OF_SNR2 + 2048;
constexpr size_t OF_SCAL = OF_RSI + 2048;
constexpr size_t WS_SMALL = OF_SCAL + 16;
constexpr size_t OF_S16  = WS_SMALL;                 // [8192][8192] u16 = 33554432 f (134MB)
constexpr size_t OF_E    = OF_S16 + 33554432;        // 33.6MB: ZbS4 -> Z2p16
constexpr size_t WS_NEED = OF_E + 8388608;           // ~210MB (ws ~1 GiB per poison fill)

#define SC_CE 0
#define SC_MASK 1
#define SC_ACC 2
#define SC_E1 3
#define SC_E2 4
#define SC_C1 5
#define SC_C2 6
#define SC_WD 7

DEVI u16 bf1(float f) { __bf16 h = (__bf16)f; return __builtin_bit_cast(u16, h); }
DEVI unsigned int bf2(float a, float b) {
  return (unsigned)bf1(a) | ((unsigned)bf1(b) << 16);
}
DEVI ull bf4(float4 v) {
  return (ull)bf2(v.x, v.y) | ((ull)bf2(v.z, v.w) << 32);
}
DEVI float b2f(u16 h) { return __uint_as_float(((unsigned)h) << 16); }
DEVI float lo16(unsigned w) { return __uint_as_float(w << 16); }
DEVI float hi16(unsigned w) { return __uint_as_float(w & 0xffff0000u); }
DEVI f32x4 mfma16(bf16x8 a, bf16x8 b, f32x4 c) {
  return __builtin_amdgcn_mfma_f32_16x16x32_bf16(a, b, c, 0, 0, 0);
}
DEVI float wsum64(float v) {
  #pragma unroll
  for (int m = 1; m < 64; m <<= 1) v += __shfl_xor(v, m, 64);
  return v;
}
DEVI float wmax64(float v) {
  #pragma unroll
  for (int m = 1; m < 64; m <<= 1) v = fmaxf(v, __shfl_xor(v, m, 64));
  return v;
}
DEVI int wargmax64(float v, int idx) {
  #pragma unroll
  for (int m = 1; m < 64; m <<= 1) {
    float ov = __shfl_xor(v, m, 64);
    int   oi = __shfl_xor(idx, m, 64);
    if (ov > v || (ov == v && oi < idx)) { v = ov; idx = oi; }
  }
  return idx;
}
DEVI void blockAtomicAdd(float* dst, float v) {
  __shared__ float red[4];
  const int tid = threadIdx.x;
  v = wsum64(v);
  __syncthreads();
  if ((tid & 63) == 0) red[tid >> 6] = v;
  __syncthreads();
  if (tid == 0) atomicAdd(dst, red[0] + red[1] + red[2] + red[3]);
}
DEVI float logsig(float z) {
  return fminf(z, 0.f) - log1pf(__expf(-fabsf(z)));
}

// ---------------- f32 -> bf16 bulk convert ------------------
__global__ __launch_bounds__(256)
void cvtbf(const float* __restrict__ src, u16* __restrict__ dst, long n8) {
  long stride = (long)gridDim.x * 256;
  for (long i = (long)blockIdx.x * 256 + threadIdx.x; i < n8; i += stride) {
    long off = i << 3;
    float4 a = *(const float4*)(src + off);
    float4 b = *(const float4*)(src + off + 4);
    uint4 o;
    o.x = bf2(a.x, a.y); o.y = bf2(a.z, a.w);
    o.z = bf2(b.x, b.y); o.w = bf2(b.z, b.w);
    *(uint4*)(dst + off) = o;
  }
}

// ---------------- prep: transpose/stack small weights to bf16 ----------------
__global__ void prep(const float* __restrict__ W0, const float* __restrict__ Wh0,
                     const float* __restrict__ W1, const float* __restrict__ Wh1,
                     const float* __restrict__ b0, const float* __restrict__ bh0,
                     u16* __restrict__ wt0, u16* __restrict__ wt1,
                     float* __restrict__ bias0) {
  int t = blockIdx.x * 256 + threadIdx.x;
  if (t < 131072) {
    int j = t >> 8, k = t & 255;
    wt0[t] = bf1((j < 256) ? W0[k * 256 + j] : Wh0[k * 256 + (j - 256)]);
  } else if (t < 196608) {
    int u = t - 131072;
    int j = u >> 9, k = u & 511;
    float v = 0.f;
    if (j < 64)  { if (k < 256)  v = W1 [k * 64 + j]; }
    else         { if (k >= 256) v = Wh1[(k - 256) * 64 + (j - 64)]; }
    wt1[u] = bf1(v);
  } else if (t < 197120) {
    int j = t - 196608;
    bias0[j] = (j < 256) ? b0[j] : bh0[j - 256];
  }
}

// ============ all-bf16 MFMA GEMM (m97 drain schedule) =======================
// C[m,n] = sum_k A16[m,k]*B16[n,k], bf16 split-stores at Cv + z*splitStride.
// LDS-BW analysis (round-10): this structure is LDS-pipe-bound; bytes/MFMA =
// (FM+FN)/(FM*FN)*1KB reads + stage writes. FM=8,FN=4 -> 576B/MFMA (vs 768 at
// 4x4) => bigger per-wave tile is the lever. MINB=2 (acc 128 VGPR).
template <int FM, int FN, int SWZ, int MLOC, int NLOG, int MINB>
__global__ __launch_bounds__(256, MINB)
void gemm_a(const u16* __restrict__ A16, const u16* __restrict__ B16,
            u16* __restrict__ Cv, int K, int Ntot, int ksteps, size_t splitStride) {
  constexpr int BM = 32 * FM, BN = 32 * FN;
  constexpr int NSEG = (BM + BN) / 16;
  constexpr int SPW = NSEG / 4;
  __shared__ __align__(16) u16 As[2][BM * 32];
  __shared__ __align__(16) u16 Bs[2][BN * 32];
  const int tid = threadIdx.x;
  const int l = tid & 63, wid = tid >> 6;
  const int wr = wid >> 1, wc = wid & 1;
  const int fr = l & 15, fg = l >> 4;

  int m0, n0;
  if (SWZ) {
    int id = blockIdx.x + gridDim.x * blockIdx.y;
    int e = id & 7, s = id >> 3;
    m0 = (e * MLOC + (s >> NLOG)) * BM;
    n0 = (s & ((1 << NLOG) - 1)) * BN;
  } else {
    m0 = blockIdx.y * BM;
    n0 = blockIdx.x * BN;
  }
  const size_t kbase = (size_t)blockIdx.z * ksteps * 32;

  const u16* gsrc[SPW];
  u16* ld0[SPW];
  u16* ld1[SPW];
  #pragma unroll
  for (int q = 0; q < SPW; ++q) {
    int s = q * 4 + wid;
    if (s < BM / 16) {
      gsrc[q] = A16 + (size_t)(m0 + s * 16 + (l & 15)) * K + kbase + ((l >> 4) << 3);
      ld0[q] = &As[0][s << 9];
      ld1[q] = &As[1][s << 9];
    } else {
      int t2 = s - BM / 16;
      gsrc[q] = B16 + (size_t)(n0 + t2 * 16 + (l & 15)) * K + kbase + ((l >> 4) << 3);
      ld0[q] = &Bs[0][t2 << 9];
      ld1[q] = &Bs[1][t2 << 9];
    }
  }
  auto stageTo = [&](int buf, int ks2) {
    int koff = ks2 * 32;
    #pragma unroll
    for (int q = 0; q < SPW; ++q) {
      u16* d = buf ? ld1[q] : ld0[q];
      __builtin_amdgcn_global_load_lds(
          (const __attribute__((address_space(1))) void*)(gsrc[q] + koff),
          (__attribute__((address_space(3))) void*)d, 16, 0, 0);
    }
  };

  f32x4 zero = {0.f, 0.f, 0.f, 0.f};
  f32x4 acc[FM][FN];
  #pragma unroll
  for (int i = 0; i < FM; ++i)
    #pragma unroll
    for (int j = 0; j < FN; ++j) acc[i][j] = zero;

  stageTo(0, 0);
  int cur = 0;
  for (int ks = 0; ks < ksteps; ++ks) {
    __syncthreads();
    if (ks + 1 < ksteps) stageTo(cur ^ 1, ks + 1);
    bf16x8 af[FM], bfv[FN];
    #pragma unroll
    for (int i = 0; i < FM; ++i)
      af[i] = *(const bf16x8*)&As[cur][((wr * FM + i) << 9) + (l << 3)];
    #pragma unroll
    for (int j = 0; j < FN; ++j)
      bfv[j] = *(const bf16x8*)&Bs[cur][((wc * FN + j) << 9) + (l << 3)];
    #pragma unroll
    for (int i = 0; i < FM; ++i)
      #pragma unroll
      for (int j = 0; j < FN; ++j)
        acc[i][j] = mfma16(af[i], bfv[j], acc[i][j]);
    cur ^= 1;
  }

  u16* outp = Cv + (size_t)blockIdx.z * splitStride;
  #pragma unroll
  for (int i = 0; i < FM; ++i)
    #pragma unroll
    for (int j = 0; j < FN; ++j)
      #pragma unroll
      for (int r = 0; r < 4; ++r) {
        int grow = m0 + wr * 16 * FM + i * 16 + (fg << 2) + r;
        int gcol = n0 + wc * 16 * FN + j * 16 + fr;
        outp[(size_t)grow * Ntot + gcol] = bf1(acc[i][j][r]);
      }
}

// -------- relu+bias + NS-way split-reduce: H16 = bf16(relu(sum Z_s + bias)) --
template <int NS>
__global__ __launch_bounds__(256)
void relupack(const u16* __restrict__ z, const float* __restrict__ bias,
              u16* __restrict__ h16) {
  int t = blockIdx.x * 256 + threadIdx.x;
  int off = t << 3;
  int col = off & 511;
  float4 c0 = *(const float4*)(bias + col);
  float4 c1 = *(const float4*)(bias + col + 4);
  float r[8] = {c0.x, c0.y, c0.z, c0.w, c1.x, c1.y, c1.z, c1.w};
  #pragma unroll
  for (int s = 0; s < NS; ++s) {
    uint4 a = *(const uint4*)(z + (size_t)s * 8192 * 512 + off);
    r[0] += lo16(a.x); r[1] += hi16(a.x);
    r[2] += lo16(a.y); r[3] += hi16(a.y);
    r[4] += lo16(a.z); r[5] += hi16(a.z);
    r[6] += lo16(a.w); r[7] += hi16(a.w);
  }
  uint4 o;
  o.x = bf2(fmaxf(r[0], 0.f), fmaxf(r[1], 0.f));
  o.y = bf2(fmaxf(r[2], 0.f), fmaxf(r[3], 0.f));
  o.z = bf2(fmaxf(r[4], 0.f), fmaxf(r[5], 0.f));
  o.w = bf2(fmaxf(r[6], 0.f), fmaxf(r[7], 0.f));
  *(uint4*)(h16 + off) = o;
}

// ------- per-row epilogue: reduce NS bf16 splits, norms, CE ------------------
template <int NS>
__global__ __launch_bounds__(256)
void rowstats(const u16* __restrict__ Z2p, const float* __restrict__ b1,
              const float* __restrict__ bh1, const float* __restrict__ labels,
              const int* __restrict__ mask, const float* __restrict__ Wc,
              float* __restrict__ outp, u16* __restrict__ gcn16, u16* __restrict__ hgcn16,
              float* __restrict__ sd, float* __restrict__ ag, float* __restrict__ bg,
              float* __restrict__ ah, float* __restrict__ bh, float* __restrict__ scal) {
  const int tid = threadIdx.x, l = tid & 63, w = tid >> 6;
  const float wa = Wc[l], wb = Wc[64 + l];
  const float bb1 = b1[l], bbh1 = bh1[l];
  float s_ce = 0.f, s_mk = 0.f, s_ac = 0.f;
  for (int it = 0; it < 8; ++it) {
    int row = blockIdx.x * 32 + it * 4 + w;
    float h1 = bb1, hg = bbh1;
    #pragma unroll
    for (int s = 0; s < NS; ++s) {
      h1 += b2f(Z2p[(size_t)s * 1048576 + row * 128 + l]);
      hg += b2f(Z2p[(size_t)s * 1048576 + row * 128 + 64 + l]);
    }
    float n1 = wsum64(h1 * h1);
    float gn = h1 / fmaxf(sqrtf(n1), 1e-12f);
    float n2 = wsum64(hg * hg);
    float hn = hg / fmaxf(sqrtf(n2), 1e-12f);
    float oc = 0.6f * gn + 0.4f * hn;
    float n3 = wsum64(oc * oc);
    float o = oc / fmaxf(sqrtf(n3), 1e-12f);
    size_t ro = (size_t)row * 64 + l;
    outp[ro] = o; gcn16[ro] = bf1(gn); hgcn16[ro] = bf1(hn);
    float sdv = wsum64(gn * hn);
    float vag = wsum64(gn * wa), vbg = wsum64(gn * wb);
    float vah = wsum64(hn * wa), vbh = wsum64(hn * wb);
    float lab = labels[ro];
    float mx = wmax64(o);
    float se = wsum64(__expf(o - mx));
    float lse = mx + __logf(se);
    float slab = wsum64(lab);
    float slo = wsum64(lab * o);
    int am_o = wargmax64(o, l);
    int am_l = wargmax64(lab, l);
    if (l == 0) {
      sd[row] = sdv; ag[row] = vag; bg[row] = vbg; ah[row] = vah; bh[row] = vbh;
      float mk = (float)mask[row];
      s_ce += (lse * slab - slo) * mk;
      s_mk += mk;
      s_ac += (am_o == am_l) ? mk : 0.f;
    }
  }
  blockAtomicAdd(&scal[SC_CE], s_ce);
  blockAtomicAdd(&scal[SC_MASK], s_mk);
  blockAtomicAdd(&scal[SC_ACC], s_ac);
}

// ------- rowsum of exp(A@B^T/tau), 2 dirs x 2 n-halves (partials) -----------
__global__ __launch_bounds__(256)
void rowsumexp2(const u16* __restrict__ G16, const u16* __restrict__ H16,
                float* __restrict__ R1, float* __restrict__ R2) {
  constexpr int PK = 72;
  __shared__ __align__(16) u16 At[64 * PK];
  __shared__ __align__(16) u16 Bt[64 * PK];
  const int bx = blockIdx.x;
  const int nh = bx >> 8, r = bx & 255, dir = r >> 7;
  const u16* __restrict__ A = dir ? H16 : G16;
  const u16* __restrict__ B = dir ? G16 : H16;
  float* __restrict__ out = (dir ? R2 : R1) + nh * 8192;
  const int tid = threadIdx.x, l = tid & 63, w = tid >> 6;
  const int m0 = (r & 127) * 64;
  #pragma unroll
  for (int p = 0; p < 2; ++p) {
    int idx = p * 256 + tid, row = idx >> 3, kq = (idx & 7) << 3;
    *(uint4*)&At[row * PK + kq] = *(const uint4*)(A + (size_t)(m0 + row) * 64 + kq);
  }
  __syncthreads();
  const int fr = l & 15, fg = l >> 4;
  bf16x8 a0 = *(const bf16x8*)&At[(w * 16 + fr) * PK + (fg << 3)];
  bf16x8 a1 = *(const bf16x8*)&At[(w * 16 + fr) * PK + 32 + (fg << 3)];
  float rs0 = 0.f, rs1 = 0.f, rs2 = 0.f, rs3 = 0.f;
  const int nbeg = nh * 4096;
  for (int n0 = nbeg; n0 < nbeg + 4096; n0 += 64) {
    __syncthreads();
    #pragma unroll
    for (int p = 0; p < 2; ++p) {
      int idx = p * 256 + tid, row = idx >> 3, kq = (idx & 7) << 3;
      *(uint4*)&Bt[row * PK + kq] = *(const uint4*)(B + (size_t)(n0 + row) * 64 + kq);
    }
    __syncthreads();
    #pragma unroll
    for (int jn = 0; jn < 4; ++jn) {
      bf16x8 b0 = *(const bf16x8*)&Bt[(jn * 16 + fr) * PK + (fg << 3)];
      bf16x8 b1 = *(const bf16x8*)&Bt[(jn * 16 + fr) * PK + 32 + (fg << 3)];
      f32x4 c = {0.f, 0.f, 0.f, 0.f};
      c = mfma16(a0, b0, c);
      c = mfma16(a1, b1, c);
      rs0 += __expf(c[0] * 2.0f);
      rs1 += __expf(c[1] * 2.0f);
      rs2 += __expf(c[2] * 2.0f);
      rs3 += __expf(c[3] * 2.0f);
    }
  }
  #pragma unroll
  for (int m = 1; m < 16; m <<= 1) {
    rs0 += __shfl_xor(rs0, m, 64);
    rs1 += __shfl_xor(rs1, m, 64);
    rs2 += __shfl_xor(rs2, m, 64);
    rs3 += __shfl_xor(rs3, m, 64);
  }
  if (fr == 0) {
    int rb = m0 + w * 16 + fg * 4;
    out[rb + 0] = rs0; out[rb + 1] = rs1; out[rb + 2] = rs2; out[rb + 3] = rs3;
  }
}

// ---------------- supervised contra, 2 dirs x 4 n-chunks --------------------
__global__ __launch_bounds__(256)
void supstats2(const u16* __restrict__ G16, const u16* __restrict__ H16,
               const int* __restrict__ tidx,
               const float* __restrict__ Wi_g, const float* __restrict__ We_g,
               float* __restrict__ SP1, float* __restrict__ SNR1,
               float* __restrict__ SP2, float* __restrict__ SNR2) {
  constexpr int PK = 72;
  __shared__ __align__(16) u16 At[64 * PK];
  __shared__ __align__(16) u16 Bt[64 * PK];
  __shared__ float Ws0[64 * 68];
  __shared__ float Ws1[64 * 68];
  const int bx = blockIdx.x;
  const int chunk = bx >> 6, sub = bx & 63, dir = sub >> 5;
  const u16* __restrict__ A = dir ? H16 : G16;
  const u16* __restrict__ B = dir ? G16 : H16;
  float* __restrict__ sp_out  = dir ? SP2 : SP1;
  float* __restrict__ sn_out  = dir ? SNR2 : SNR1;
  const int tid = threadIdx.x, l = tid & 63, w = tid >> 6;
  const int m0 = (sub & 31) * 64;
  #pragma unroll
  for (int p = 0; p < 2; ++p) {
    int idx = p * 256 + tid, row = idx >> 3, kq = (idx & 7) << 3;
    int gr = tidx[m0 + row];
    *(uint4*)&At[row * PK + kq] = *(const uint4*)(A + (size_t)gr * 64 + kq);
  }
  __syncthreads();
  const int fr = l & 15, fg = l >> 4;
  bf16x8 a0 = *(const bf16x8*)&At[(w * 16 + fr) * PK + (fg << 3)];
  bf16x8 a1 = *(const bf16x8*)&At[(w * 16 + fr) * PK + 32 + (fg << 3)];
  float sp0 = 0, sp1 = 0, sp2 = 0, sp3 = 0, sn0 = 0, sn1 = 0, sn2 = 0, sn3 = 0;
  const int nbeg = chunk * 512;
  for (int n0 = nbeg; n0 < nbeg + 512; n0 += 64) {
    __syncthreads();
    #pragma unroll
    for (int p = 0; p < 2; ++p) {
      int idx = p * 256 + tid, row = idx >> 3, kq = (idx & 7) << 3;
      int gr = tidx[n0 + row];
      *(uint4*)&Bt[row * PK + kq] = *(const uint4*)(B + (size_t)gr * 64 + kq);
    }
    #pragma unroll
    for (int p = 0; p < 4; ++p) {
      int idx = p * 256 + tid, row = idx >> 4, kq = (idx & 15) << 2;
      *(float4*)&Ws0[row * 68 + kq] = *(const float4*)(Wi_g + (size_t)(m0 + row) * 2048 + n0 + kq);
      *(float4*)&Ws1[row * 68 + kq] = *(const float4*)(We_g + (size_t)(m0 + row) * 2048 + n0 + kq);
    }
    __syncthreads();
    #pragma unroll
    for (int jn = 0; jn < 4; ++jn) {
      bf16x8 b0 = *(const bf16x8*)&Bt[(jn * 16 + fr) * PK + (fg << 3)];
      bf16x8 b1 = *(const bf16x8*)&Bt[(jn * 16 + fr) * PK + 32 + (fg << 3)];
      f32x4 c = {0.f, 0.f, 0.f, 0.f};
      c = mfma16(a0, b0, c);
      c = mfma16(a1, b1, c);
      int cl = jn * 16 + fr;
      int rl = w * 16 + fg * 4;
      float e0 = __expf(c[0] * 2.0f);
      float e1 = __expf(c[1] * 2.0f);
      float e2 = __expf(c[2] * 2.0f);
      float e3 = __expf(c[3] * 2.0f);
      sp0 += e0 * Ws0[(rl + 0) * 68 + cl]; sn0 += e0 * Ws1[(rl + 0) * 68 + cl];
      sp1 += e1 * Ws0[(rl + 1) * 68 + cl]; sn1 += e1 * Ws1[(rl + 1) * 68 + cl];
      sp2 += e2 * Ws0[(rl + 2) * 68 + cl]; sn2 += e2 * Ws1[(rl + 2) * 68 + cl];
      sp3 += e3 * Ws0[(rl + 3) * 68 + cl]; sn3 += e3 * Ws1[(rl + 3) * 68 + cl];
    }
  }
  #pragma unroll
  for (int m = 1; m < 16; m <<= 1) {
    sp0 += __shfl_xor(sp0, m, 64); sn0 += __shfl_xor(sn0, m, 64);
    sp1 += __shfl_xor(sp1, m, 64); sn1 += __shfl_xor(sn1, m, 64);
    sp2 += __shfl_xor(sp2, m, 64); sn2 += __shfl_xor(sn2, m, 64);
    sp3 += __shfl_xor(sp3, m, 64); sn3 += __shfl_xor(sn3, m, 64);
  }
  if (fr == 0) {
    int rb = m0 + w * 16 + fg * 4;
    atomicAdd(&sp_out[rb + 0], sp0); atomicAdd(&sn_out[rb + 0], sn0);
    atomicAdd(&sp_out[rb + 1], sp1); atomicAdd(&sn_out[rb + 1], sn1);
    atomicAdd(&sp_out[rb + 2], sp2); atomicAdd(&sn_out[rb + 2], sn2);
    atomicAdd(&sp_out[rb + 3], sp3); atomicAdd(&sn_out[rb + 3], sn3);
  }
}

// ---------------- small reductions ----------------
__global__ __launch_bounds__(256)
void rowsum2048(const float* __restrict__ Wi, float* __restrict__ rsi) {
  int l = threadIdx.x & 63, w = threadIdx.x >> 6;
  int row = blockIdx.x * 4 + w;
  float s = 0.f;
  #pragma unroll
  for (int p = 0; p < 8; ++p) {
    int c = (p * 64 + l) << 2;
    float4 v = *(const float4*)(Wi + (size_t)row * 2048 + c);
    s += v.x + v.y + v.z + v.w;
  }
  s = wsum64(s);
  if (l == 0) rsi[row] = s;
}

__global__ __launch_bounds__(256)
void edgered(const int* __restrict__ ei, const int* __restrict__ ej,
             const float* __restrict__ ag, const float* __restrict__ bg,
             const float* __restrict__ ah, const float* __restrict__ bh,
             const float* __restrict__ bc, float* __restrict__ scal) {
  int t = blockIdx.x * 256 + threadIdx.x;
  float bcv = bc[0];
  float s1 = 0.f, s2 = 0.f;
  for (int e = t; e < EE; e += 65536) {
    int i = ei[e], j = ej[e];
    s1 += logsig(ag[i] + bh[j] + bcv);
    s2 += logsig(ah[i] + bg[j] + bcv);
  }
  blockAtomicAdd(&scal[SC_E1], s1);
  blockAtomicAdd(&scal[SC_E2], s2);
}

__global__ __launch_bounds__(256)
void contrared(const float* __restrict__ sd, const float* __restrict__ r1,
               const float* __restrict__ r2, float* __restrict__ scal) {
  int i = blockIdx.x * 256 + threadIdx.x;
  constexpr float LOGN = 9.01091334728f;  // ln(8192)
  float ra = r1[i] + r1[8192 + i];
  float rb = r2[i] + r2[8192 + i];
  float v = 4.f * sd[i] - __logf(ra) - __logf(rb) + 2.f * LOGN;
  blockAtomicAdd(&scal[SC_C1], v);
}

__global__ __launch_bounds__(256)
void supred(const float* __restrict__ sp1, const float* __restrict__ snr1,
            const float* __restrict__ sp2, const float* __restrict__ snr2,
            const float* __restrict__ rsi, float* __restrict__ scal) {
  int i = blockIdx.x * 256 + threadIdx.x;
  float rs = rsi[i];
  float a1 = sp1[i], d1 = (snr1[i] + a1) * (1.f / 2047.f);
  float a2 = sp2[i], d2 = (snr2[i] + a2) * (1.f / 2047.f);
  float v = __logf(a1 / rs / d1) + __logf(a2 / rs / d2);
  blockAtomicAdd(&scal[SC_C2], v);
}

__global__ __launch_bounds__(256)
void wdsum(const float* __restrict__ W0, const float* __restrict__ b0,
           const float* __restrict__ W1, const float* __restrict__ b1,
           const float* __restrict__ Wc, const float* __restrict__ bc,
           float* __restrict__ scal) {
  int t = threadIdx.x;
  float s = 0.f;
  for (int i = t; i < 16384; i += 256) {
    float4 v = *(const float4*)(W0 + i * 4);
    s += v.x * v.x + v.y * v.y + v.z * v.z + v.w * v.w;
  }
  for (int i = t; i < 4096; i += 256) {
    float4 v = *(const float4*)(W1 + i * 4);
    s += v.x * v.x + v.y * v.y + v.z * v.z + v.w * v.w;
  }
  if (t < 256) { float v = b0[t]; s += v * v; }
  if (t < 64)  { float v = b1[t]; s += v * v; }
  if (t < 128) { float v = Wc[t]; s += v * v; }
  if (t == 0)  { float v = bc[0]; s += v * v; }
  blockAtomicAdd(&scal[SC_WD], s);
}

__global__ void finalk(const float* __restrict__ scal, float* __restrict__ dst) {
  float masks = scal[SC_MASK];
  float loss = scal[SC_CE] / masks
             + 0.4f * (-(scal[SC_E1] + scal[SC_E2]) * (1.f / 262144.f))
             - 0.9f * scal[SC_C1] * (1.f / 16384.f)
             - 0.9f * scal[SC_C2] * (1.f / 4096.f)
             + 5e-4f * 0.5f * scal[SC_WD];
  dst[0] = loss;
  dst[1] = scal[SC_ACC] / masks;
}

extern "C" void kernel_launch(void* const* d_in, const int* in_sizes, int n_in,
                              void* d_out, int out_size, void* d_ws, size_t ws_size,
                              hipStream_t stream) {
  const float* features = (const float*)d_in[0];
  const float* support  = (const float*)d_in[1];
  const float* labels   = (const float*)d_in[2];
  const float* intra    = (const float*)d_in[3];
  const float* inter    = (const float*)d_in[4];
  const float* W0  = (const float*)d_in[5];
  const float* b0  = (const float*)d_in[6];
  const float* W1  = (const float*)d_in[7];
  const float* b1  = (const float*)d_in[8];
  const float* Wh0 = (const float*)d_in[9];
  const float* bh0 = (const float*)d_in[10];
  const float* Wh1 = (const float*)d_in[11];
  const float* bh1 = (const float*)d_in[12];
  const float* Wc  = (const float*)d_in[13];
  const float* bc  = (const float*)d_in[14];
  const int* ei    = (const int*)d_in[15];
  const int* ej    = (const int*)d_in[16];
  const int* tidx  = (const int*)d_in[17];
  const int* mask  = (const int*)d_in[18];

  if (ws_size < WS_NEED * sizeof(float)) return;

  float* ws = (float*)d_ws;
  u16*   WT0b  = (u16*)(ws + OF_WT0b);
  u16*   WT1b  = (u16*)(ws + OF_WT1b);
  float* BIA0  = ws + OF_BIA0;
  u16*   X16   = (u16*)(ws + OF_X16);   // [8192][256]
  u16*   XWT16 = (u16*)(ws + OF_A);     // [512][8192]
  u16*   H16   = (u16*)(ws + OF_A);     // [8192][512] (alias; XWT16 dead)
  u16*   HWT16 = (u16*)(ws + OF_D);     // [128][8192]
  u16*   G16   = (u16*)(ws + OF_A);               // [8192][64]
  u16*   HG16  = (u16*)(ws + OF_A + 262144);      // [8192][64]
  u16*   S16   = (u16*)(ws + OF_S16);   // [8192][8192]
  u16*   ZbS4  = (u16*)(ws + OF_E);     // 4 x [8192][512] splits
  u16*   Z2p16 = (u16*)(ws + OF_E);     // 16 x [8192][128] splits (ZbS4 dead)
  float* SD   = ws + OF_SD;
  float* R1   = ws + OF_R1;
  float* R2   = ws + OF_R2;
  float* AG   = ws + OF_AG;
  float* BG   = ws + OF_BG;
  float* AH   = ws + OF_AH;
  float* BH   = ws + OF_BH;
  float* SP1  = ws + OF_SP1;
  float* SNR1 = ws + OF_SNR1;
  float* SP2  = ws + OF_SP2;
  float* SNR2 = ws + OF_SNR2;
  float* RSI  = ws + OF_RSI;
  float* SCAL = ws + OF_SCAL;
  float* outp = (float*)d_out;

  hipMemsetAsync(SCAL, 0, 16 * sizeof(float), stream);
  hipMemsetAsync(SP1, 0, 4 * 2048 * sizeof(float), stream);
  prep<<<770, 256, 0, stream>>>(W0, Wh0, W1, Wh1, b0, bh0, WT0b, WT1b, BIA0);
  cvtbf<<<256, 256, 0, stream>>>(features, X16, 262144);
  cvtbf<<<4096, 256, 0, stream>>>(support, S16, 8388608);

  // gemm1: XWT16[512][8192] = bf16((X @ [W0|Wh0])^T)  128x128 tile, ksteps=8
  gemm_a<4, 4, 0, 0, 0, 4><<<dim3(64, 4, 1), 256, 0, stream>>>(
      WT0b, X16, XWT16, 256, 8192, 8, 0);

  // gemm2: ZbS4[z] = bf16(S16 @ XW partial), 256x128 tile, split-K=4
  gemm_a<8, 4, 1, 4, 2, 2><<<dim3(4, 32, 4), 256, 0, stream>>>(
      S16, XWT16, ZbS4, 8192, 512, 64, (size_t)8192 * 512);
  relupack<4><<<2048, 256, 0, stream>>>(ZbS4, BIA0, H16);

  // gemm3: HWT16[128][8192] = bf16(([h0@W1 | g0@Wh1])^T)  64x128, ksteps=16
  gemm_a<2, 4, 0, 0, 0, 4><<<dim3(64, 2, 1), 256, 0, stream>>>(
      WT1b, H16, HWT16, 512, 8192, 16, 0);

  // gemm4: Z2p16[z] = bf16(S16 @ HW partial), 256x128 tile, split-K=16
  gemm_a<8, 4, 1, 4, 0, 2><<<dim3(1, 32, 16), 256, 0, stream>>>(
      S16, HWT16, Z2p16, 8192, 128, 16, (size_t)8192 * 128);
  rowstats<16><<<256, 256, 0, stream>>>(Z2p16, b1, bh1, labels, mask, Wc,
                                        outp, G16, HG16, SD, AG, BG, AH, BH, SCAL);

  rowsumexp2<<<512, 256, 0, stream>>>(G16, HG16, R1, R2);
  rowsum2048<<<512, 256, 0, stream>>>(intra, RSI);
  supstats2<<<256, 256, 0, stream>>>(G16, HG16, tidx, intra, inter,
                                     SP1, SNR1, SP2, SNR2);
  edgered<<<256, 256, 0, stream>>>(ei, ej, AG, BG, AH, BH, bc, SCAL);
  contrared<<<32, 256, 0, stream>>>(SD, R1, R2, SCAL);
  supred<<<8, 256, 0, stream>>>(SP1, SNR1, SP2, SNR2, RSI, SCAL);
  wdsum<<<1, 256, 0, stream>>>(W0, b0, W1, b1, Wc, bc, SCAL);
  finalk<<<1, 1, 0, stream>>>(SCAL, outp + (size_t)8192 * 64);
}